// Round 10
// baseline (59.251 us; speedup 1.0000x reference)
//
#include <hip/hip_runtime.h>
#include <hip/hip_fp16.h>
#include <math.h>

// Problem constants
#define B_   8
#define C1   256
#define HW1  4096   // 64*64
#define C2   512
#define HW2  1024   // 32*32

#define CCH  8      // channels per block
#define HWT  1024   // hw elements per block (256 threads * 4)
#define NCH1 32     // C1/CCH
#define NCH2 64     // C2/CCH
#define NT1  4      // HW1/HWT
#define NT2  1

#define NB1  (B_*NT1*NCH1)   // 1024
#define NB2  (B_*NCH2)       // 512
#define NBS  (NB1+NB2)       // 1536

// ---------------- ws layout (floats); nothing read before written ----------------
#define F_LATP  0                          // 32 lat partials
#define F_SL1P  (F_LATP + 32)              // NB1 slam1 partial slots
#define F_SL2P  (F_SL1P + NB1)             // NB2 slam2 partial slots
#define F_CP1S  (F_SL2P + NB2)             // Cs1 partials [B][C1][NT1] fp32
#define F_CP1T  (F_CP1S + B_*C1*NT1)
#define F_CP2S  (F_CP1T + B_*C1*NT1)       // Cs2 [B][C2] fp32
#define F_CP2T  (F_CP2S + B_*C2)
#define F_GS1S  (F_CP2T + B_*C2)           // Gs1 [B][HW1] fp32
#define F_GS1T  (F_GS1S + B_*HW1)
#define F_GS2S  (F_GS1T + B_*HW1)          // Gs2 [B][HW2] fp32
#define F_GS2T  (F_GS2S + B_*HW2)
#define F_MS1   (F_GS2T + B_*HW2)
#define F_MC1   (F_MS1 + B_*HW1)
#define F_MS2   (F_MC1 + B_*C1)
#define F_MC2   (F_MS2 + B_*HW2)
#define F_APH   (F_MC2 + B_*C2)            // interleaved {s,t} fp16 As-partial records
// h8 record = 4 hw positions x {s,t} = 16 B. counts:
#define NP1     (NCH1*B_*(HW1/4))          // level-1 records (262144)
#define NP2     (NCH2*B_*(HW2/4))          // level-2 records (131072)
#define APH_FLOATS ((NP1 + NP2) * 4)
#define F_D8    (F_APH + APH_FLOATS)       // fp8 d^2 region, thread-linear (uint-indexed)
#define ND1U    (NB1*256*8)                // level-1 uints (2.097M)
#define ND2U    (NB2*256*8)                // level-2 uints (1.049M)

struct alignas(16) h8 { __half2 sa, sb, ta, tb; };   // 4 hw x {s,t}
typedef float v2f __attribute__((ext_vector_type(2)));

__device__ __forceinline__ float wave_reduce_sum(float v) {
#pragma unroll
    for (int off = 1; off < 64; off <<= 1) v += __shfl_xor(v, off, 64);
    return v;
}
__device__ __forceinline__ float wave_reduce_max(float v) {
#pragma unroll
    for (int off = 1; off < 64; off <<= 1) v = fmaxf(v, __shfl_xor(v, off, 64));
    return v;
}
__device__ __forceinline__ float block_reduce_sum(float v, float* red) {
    const int lane = threadIdx.x & 63, wid = threadIdx.x >> 6;
    v = wave_reduce_sum(v);
    if (lane == 0) red[wid] = v;
    __syncthreads();
    v = red[0] + red[1] + red[2] + red[3];
    __syncthreads();
    return v;
}
__device__ __forceinline__ float block_reduce_max(float v, float* red) {
    const int lane = threadIdx.x & 63, wid = threadIdx.x >> 6;
    v = wave_reduce_max(v);
    if (lane == 0) red[wid] = v;
    __syncthreads();
    v = fmaxf(fmaxf(red[0], red[1]), fmaxf(red[2], red[3]));
    __syncthreads();
    return v;
}

// HW fp8 pack/unpack (gfx950 OCP e4m3fn; self-consistent)
__device__ __forceinline__ unsigned int pack4_fp8(float q0, float q1, float q2, float q3) {
    int u = 0;
    u = __builtin_amdgcn_cvt_pk_fp8_f32(q0, q1, u, false);
    u = __builtin_amdgcn_cvt_pk_fp8_f32(q2, q3, u, true);
    return (unsigned int)u;
}

// ---------------- stats: As/Cs partials + d^2 fp8 stash (thread-linear) ----------------
template<int C, int HW, int NT>
__device__ void stats_level(const float* __restrict__ s, const float* __restrict__ t,
                            h8* __restrict__ AP,          // this level's record array
                            float* __restrict__ CPs, float* __restrict__ CPt,
                            unsigned int* __restrict__ dthr,  // this thread's 8-uint d8 slot
                            int b, int tile, int chunk, float (*part)[256]) {
    const int tid = threadIdx.x, lane = tid & 63, wid = tid >> 6;
    const int hw0 = tile * HWT + tid * 4;
    const int c0 = chunk * CCH;
    const size_t base = ((size_t)(b * C + c0)) * HW + hw0;
    const float4* ps = reinterpret_cast<const float4*>(s + base);
    const float4* pt = reinterpret_cast<const float4*>(t + base);
    const int cstride = HW / 4;

    float as0 = 0.f, as1 = 0.f, as2 = 0.f, as3 = 0.f;
    float at0 = 0.f, at1 = 0.f, at2 = 0.f, at3 = 0.f;
    float css[CCH], cst[CCH];
    unsigned int pk8[CCH];

#pragma unroll
    for (int ci = 0; ci < CCH; ++ci) {
        float4 vs = ps[(size_t)ci * cstride];
        float4 vt = pt[(size_t)ci * cstride];
        float a0 = fabsf(vs.x), a1 = fabsf(vs.y), a2 = fabsf(vs.z), a3 = fabsf(vs.w);
        float b0 = fabsf(vt.x), b1 = fabsf(vt.y), b2 = fabsf(vt.z), b3 = fabsf(vt.w);
        as0 += a0; as1 += a1; as2 += a2; as3 += a3;
        at0 += b0; at1 += b1; at2 += b2; at3 += b3;
        css[ci] = (a0 + a1) + (a2 + a3);
        cst[ci] = (b0 + b1) + (b2 + b3);
        const float d0 = vs.x - vt.x, d1 = vs.y - vt.y, d2 = vs.z - vt.z, d3 = vs.w - vt.w;
        pk8[ci] = pack4_fp8(d0 * d0, d1 * d1, d2 * d2, d3 * d3);
    }
    // d^2: 2x 16B coalesced stores (thread-linear layout, slam uses identical mapping)
    *reinterpret_cast<uint4*>(dthr)     = make_uint4(pk8[0], pk8[1], pk8[2], pk8[3]);
    *reinterpret_cast<uint4*>(dthr + 4) = make_uint4(pk8[4], pk8[5], pk8[6], pk8[7]);

    // As partials: one 16B record {s,t}
    h8 rec;
    rec.sa = __floats2half2_rn(as0, as1); rec.sb = __floats2half2_rn(as2, as3);
    rec.ta = __floats2half2_rn(at0, at1); rec.tb = __floats2half2_rn(at2, at3);
    AP[((size_t)chunk * B_ + b) * (HW / 4) + (hw0 >> 2)] = rec;

    // Cs partials: LDS transpose + wave reduce, fp32 plain stores
#pragma unroll
    for (int ci = 0; ci < CCH; ++ci) {
        part[ci][tid] = css[ci];
        part[CCH + ci][tid] = cst[ci];
    }
    __syncthreads();
#pragma unroll
    for (int k = 0; k < 4; ++k) {
        const int r = wid * 4 + k;
        const float* cb = part[r];
        float v = (cb[lane] + cb[lane + 64]) + (cb[lane + 128] + cb[lane + 192]);
        v = wave_reduce_sum(v);
        if (lane == 0) {
            const int cc = r & (CCH - 1);
            float* dst = (r < CCH) ? CPs : CPt;
            dst[((size_t)b * C + c0 + cc) * NT + tile] = v;
        }
    }
}

__global__ __launch_bounds__(256) void stats_fast(const float* __restrict__ s1, const float* __restrict__ t1,
                                                  const float* __restrict__ s2, const float* __restrict__ t2,
                                                  float* ws) {
    __shared__ float part[2 * CCH][256];   // 16 KB
    const int bid = blockIdx.x, tid = threadIdx.x;
    h8* ap = reinterpret_cast<h8*>(ws + F_APH);
    unsigned int* d8 = reinterpret_cast<unsigned int*>(ws + F_D8);
    if (bid < NB1) {
        const int b = bid >> 7, rem = bid & 127, tile = rem >> 5, chunk = rem & 31;
        unsigned int* dthr = d8 + ((size_t)bid * 256 + tid) * 8;
        stats_level<C1, HW1, NT1>(s1, t1, ap, ws + F_CP1S, ws + F_CP1T, dthr, b, tile, chunk, part);
    } else {
        const int bid2 = bid - NB1;
        const int b = bid2 >> 6, chunk = bid2 & 63;
        unsigned int* dthr = d8 + ND1U + ((size_t)bid2 * 256 + tid) * 8;
        stats_level<C2, HW2, NT2>(s2, t2, ap + NP1, ws + F_CP2S, ws + F_CP2T, dthr, b, 0, chunk, part);
    }
}

// ---------------- reduce_as: fold interleaved fp16 As records -> fp32 Gs ----------------
__global__ __launch_bounds__(256) void reduce_as(float* __restrict__ ws) {
    const int gid = blockIdx.x * 256 + threadIdx.x;
    const h8* ap = reinterpret_cast<const h8*>(ws + F_APH);
    if (gid < B_ * (HW1 / 4)) {                        // level 1: 8192 threads
        const int b = gid >> 10, q = gid & 1023;
        const h8* src = ap + (size_t)b * (HW1 / 4) + q;
        float4 aS = make_float4(0.f, 0.f, 0.f, 0.f);
        float4 aT = make_float4(0.f, 0.f, 0.f, 0.f);
#pragma unroll
        for (int k = 0; k < NCH1; ++k) {
            const h8 v = src[(size_t)k * B_ * (HW1 / 4)];
            const float2 s0 = __half22float2(v.sa), s1 = __half22float2(v.sb);
            const float2 t0 = __half22float2(v.ta), t1 = __half22float2(v.tb);
            aS.x += s0.x; aS.y += s0.y; aS.z += s1.x; aS.w += s1.y;
            aT.x += t0.x; aT.y += t0.y; aT.z += t1.x; aT.w += t1.y;
        }
        reinterpret_cast<float4*>(ws + F_GS1S)[(size_t)b * (HW1 / 4) + q] = aS;
        reinterpret_cast<float4*>(ws + F_GS1T)[(size_t)b * (HW1 / 4) + q] = aT;
    } else if (gid < B_ * (HW1 / 4) + B_ * (HW2 / 4)) { // level 2: 2048 threads
        const int g2 = gid - B_ * (HW1 / 4);
        const int b = g2 >> 8, q = g2 & 255;
        const h8* src = ap + NP1 + (size_t)b * (HW2 / 4) + q;
        float4 aS = make_float4(0.f, 0.f, 0.f, 0.f);
        float4 aT = make_float4(0.f, 0.f, 0.f, 0.f);
#pragma unroll
        for (int k = 0; k < NCH2; ++k) {
            const h8 v = src[(size_t)k * B_ * (HW2 / 4)];
            const float2 s0 = __half22float2(v.sa), s1 = __half22float2(v.sb);
            const float2 t0 = __half22float2(v.ta), t1 = __half22float2(v.tb);
            aS.x += s0.x; aS.y += s0.y; aS.z += s1.x; aS.w += s1.y;
            aT.x += t0.x; aT.y += t0.y; aT.z += t1.x; aT.w += t1.y;
        }
        reinterpret_cast<float4*>(ws + F_GS2S)[(size_t)b * (HW2 / 4) + q] = aS;
        reinterpret_cast<float4*>(ws + F_GS2T)[(size_t)b * (HW2 / 4) + q] = aT;
    }
}

// ---------------- softmax + lat ----------------
__global__ __launch_bounds__(256) void softmax_fast(float* ws) {
    __shared__ float sa[HW1], sb[HW1];
    __shared__ float red[4];
    const int bid = blockIdx.x;
    const int b = bid >> 2, m = bid & 3;
    const int tid = threadIdx.x;

    int n; float scale, mult; float* M;
    if (m == 0)      { n = HW1; scale = 1.0f / C1;  mult = (float)HW1; M = ws + F_MS1 + b * HW1; }
    else if (m == 1) { n = C1;  scale = 1.0f / HW1; mult = (float)C1;  M = ws + F_MC1 + b * C1;  }
    else if (m == 2) { n = HW2; scale = 1.0f / C2;  mult = (float)HW2; M = ws + F_MS2 + b * HW2; }
    else             { n = C2;  scale = 1.0f / HW2; mult = (float)C2;  M = ws + F_MC2 + b * C2;  }

    if (m == 0) {
        const float* As = ws + F_GS1S + b * HW1;
        const float* At = ws + F_GS1T + b * HW1;
        for (int i = tid; i < HW1; i += 256) { sa[i] = As[i] * scale; sb[i] = At[i] * scale; }
    } else if (m == 1) {
        if (tid < C1) {
            float4 v = *reinterpret_cast<const float4*>(ws + F_CP1S + ((size_t)b * C1 + tid) * 4);
            float4 w = *reinterpret_cast<const float4*>(ws + F_CP1T + ((size_t)b * C1 + tid) * 4);
            sa[tid] = ((v.x + v.y) + (v.z + v.w)) * scale;
            sb[tid] = ((w.x + w.y) + (w.z + w.w)) * scale;
        }
    } else if (m == 2) {
        const float* As = ws + F_GS2S + b * HW2;
        const float* At = ws + F_GS2T + b * HW2;
        for (int i = tid; i < HW2; i += 256) { sa[i] = As[i] * scale; sb[i] = At[i] * scale; }
    } else {
        for (int i = tid; i < C2; i += 256) {
            sa[i] = ws[F_CP2S + b * C2 + i] * scale;
            sb[i] = ws[F_CP2T + b * C2 + i] * scale;
        }
    }
    __syncthreads();

    const float invT = 2.0f;  // 1/T, T=0.5
    float latp = 0.f, mx = -3.0e38f;
    for (int i = tid; i < n; i += 256) {
        float d = sa[i] - sb[i];
        latp += d * d;
        mx = fmaxf(mx, (sa[i] + sb[i]) * invT);
    }
    const float mxall = block_reduce_max(mx, red);
    const float latall = block_reduce_sum(latp, red);
    if (tid == 0) ws[F_LATP + bid] = latall;

    float se = 0.f;
    for (int i = tid; i < n; i += 256) se += expf((sa[i] + sb[i]) * invT - mxall);
    const float seall = block_reduce_sum(se, red);
    const float inv = mult / seall;
    for (int i = tid; i < n; i += 256)
        M[i] = expf((sa[i] + sb[i]) * invT - mxall) * inv;
}

// ---------------- slam from thread-linear fp8 d^2 stash ----------------
template<int C, int HW>
__device__ float slam_level(const unsigned int* __restrict__ dthr,
                            const float* Ms, const float* Mc,
                            int b, int tile, int chunk, float* mc, float* red) {
    const int tid = threadIdx.x;
    const int hw0 = tile * HWT + tid * 4;
    const int c0 = chunk * CCH;
    if (tid < CCH) mc[tid] = Mc[b * C + c0 + tid];
    __syncthreads();

    const uint4 u0 = *reinterpret_cast<const uint4*>(dthr);
    const uint4 u1 = *reinterpret_cast<const uint4*>(dthr + 4);
    unsigned int pk8[CCH] = {u0.x, u0.y, u0.z, u0.w, u1.x, u1.y, u1.z, u1.w};

    float a0 = 0.f, a1 = 0.f, a2 = 0.f, a3 = 0.f;
#pragma unroll
    for (int ci = 0; ci < CCH; ++ci) {
        const int u = (int)pk8[ci];
        const float m = mc[ci];
        const v2f lo = __builtin_amdgcn_cvt_pk_f32_fp8(u, false);
        const v2f hi = __builtin_amdgcn_cvt_pk_f32_fp8(u, true);
        a0 = fmaf(m, lo.x, a0);
        a1 = fmaf(m, lo.y, a1);
        a2 = fmaf(m, hi.x, a2);
        a3 = fmaf(m, hi.y, a3);
    }
    const float4 msv = *reinterpret_cast<const float4*>(Ms + b * HW + hw0);
    float acc = a0 * msv.x + a1 * msv.y + a2 * msv.z + a3 * msv.w;
    return block_reduce_sum(acc, red);
}

__global__ __launch_bounds__(256) void slam_d2(float* __restrict__ ws) {
    __shared__ float mc[CCH];
    __shared__ float red[4];
    const int bid = blockIdx.x, tid = threadIdx.x;
    const unsigned int* d8 = reinterpret_cast<const unsigned int*>(ws + F_D8);

    if (bid < NB1) {
        const int b = bid >> 7, rem = bid & 127, tile = rem >> 5, chunk = rem & 31;
        const unsigned int* dthr = d8 + ((size_t)bid * 256 + tid) * 8;
        float acc = slam_level<C1, HW1>(dthr, ws + F_MS1, ws + F_MC1, b, tile, chunk, mc, red);
        if (tid == 0) ws[F_SL1P + bid] = acc;
    } else {
        const int bid2 = bid - NB1;
        const int b = bid2 >> 6, chunk = bid2 & 63;
        const unsigned int* dthr = d8 + ND1U + ((size_t)bid2 * 256 + tid) * 8;
        float acc = slam_level<C2, HW2>(dthr, ws + F_MS2, ws + F_MC2, b, 0, chunk, mc, red);
        if (tid == 0) ws[F_SL2P + bid2] = acc;
    }
}

// ---------------- final reduction ----------------
__global__ __launch_bounds__(256) void final_fast(const float* __restrict__ ws, float* __restrict__ out) {
    __shared__ float red[4];
    const int tid = threadIdx.x;
    float lat = 0.f, p1 = 0.f, p2 = 0.f;
    for (int i = tid; i < 32; i += 256)   lat += ws[F_LATP + i];
    for (int i = tid; i < NB1; i += 256)  p1 += ws[F_SL1P + i];
    for (int i = tid; i < NB2; i += 256)  p2 += ws[F_SL2P + i];
    lat = block_reduce_sum(lat, red);
    p1 = block_reduce_sum(p1, red);
    p2 = block_reduce_sum(p2, red);
    if (tid == 0) {
        const float lam = sqrtf(p1) + sqrtf(p2);
        const float att = (4e-4f * lat + 2e-2f * lam) / 16.0f;
        out[0] = att * 8.0f;
        out[1] = att;
    }
}

// ============================== launch ==============================

extern "C" void kernel_launch(void* const* d_in, const int* in_sizes, int n_in,
                              void* d_out, int out_size, void* d_ws, size_t ws_size,
                              hipStream_t stream) {
    (void)in_sizes; (void)n_in; (void)out_size; (void)ws_size;
    const float* s1 = (const float*)d_in[1];
    const float* t1 = (const float*)d_in[2];
    const float* s2 = (const float*)d_in[3];
    const float* t2 = (const float*)d_in[4];
    float* ws = (float*)d_ws;
    float* out = (float*)d_out;

    stats_fast<<<NBS, 256, 0, stream>>>(s1, t1, s2, t2, ws);
    reduce_as<<<40, 256, 0, stream>>>(ws);
    softmax_fast<<<32, 256, 0, stream>>>(ws);
    slam_d2<<<NBS, 256, 0, stream>>>(ws);
    final_fast<<<1, 256, 0, stream>>>(ws, out);
}

// Round 11
// 42.060 us; speedup vs baseline: 1.4087x; 1.4087x over previous
//
#include <hip/hip_runtime.h>
#include <hip/hip_fp16.h>
#include <math.h>

// Problem constants
#define B_   8
#define C1   256
#define HW1  4096   // 64*64
#define C2   512
#define HW2  1024   // 32*32

#define CCH  8      // channels per block
#define HWT  1024   // hw elements per block (256 threads * 4)
#define NCH1 32     // C1/CCH
#define NCH2 64     // C2/CCH
#define NT1  4      // HW1/HWT
#define NT2  1

#define NB1  (B_*NT1*NCH1)   // 1024
#define NB2  (B_*NCH2)       // 512
#define NBS  (NB1+NB2)       // 1536

// ---------------- ws layout (floats); nothing read before written ----------------
#define F_LATP  0                          // 32 lat partials
#define F_SL1P  (F_LATP + 32)              // NB1 slam1 partial slots
#define F_SL2P  (F_SL1P + NB1)             // NB2 slam2 partial slots
#define F_CP1S  (F_SL2P + NB2)             // Cs1 partials [B][C1][NT1] fp32
#define F_CP1T  (F_CP1S + B_*C1*NT1)
#define F_CP2S  (F_CP1T + B_*C1*NT1)       // Cs2 [B][C2] fp32
#define F_CP2T  (F_CP2S + B_*C2)
#define F_GS1S  (F_CP2T + B_*C2)           // Gs1 [B][HW1] fp32
#define F_GS1T  (F_GS1S + B_*HW1)
#define F_GS2S  (F_GS1T + B_*HW1)          // Gs2 [B][HW2] fp32
#define F_GS2T  (F_GS2S + B_*HW2)
#define F_MS1   (F_GS2T + B_*HW2)
#define F_MC1   (F_MS1 + B_*HW1)
#define F_MS2   (F_MC1 + B_*C1)
#define F_MC2   (F_MS2 + B_*HW2)
#define F_APH   (F_MC2 + B_*C2)            // fp16 As-partial region (even float offset)
// half-indexed offsets within AP region:
#define NH1     (NCH1*B_*HW1)              // halves per level-1 tensor
#define NH2     (NCH2*B_*HW2)              // halves per level-2 tensor
#define APH_FLOATS ((2*NH1 + 2*NH2) / 2)
#define F_D8    (F_APH + APH_FLOATS)       // fp8 d^2 region (byte-indexed)
#define ND1     (B_*C1*HW1)                // bytes level 1
#define ND2     (B_*C2*HW2)                // bytes level 2

struct alignas(8) h4 { __half2 a, b; };
typedef float v2f __attribute__((ext_vector_type(2)));

__device__ __forceinline__ float wave_reduce_sum(float v) {
#pragma unroll
    for (int off = 1; off < 64; off <<= 1) v += __shfl_xor(v, off, 64);
    return v;
}
__device__ __forceinline__ float wave_reduce_max(float v) {
#pragma unroll
    for (int off = 1; off < 64; off <<= 1) v = fmaxf(v, __shfl_xor(v, off, 64));
    return v;
}
__device__ __forceinline__ float block_reduce_sum(float v, float* red) {
    const int lane = threadIdx.x & 63, wid = threadIdx.x >> 6;
    v = wave_reduce_sum(v);
    if (lane == 0) red[wid] = v;
    __syncthreads();
    v = red[0] + red[1] + red[2] + red[3];
    __syncthreads();
    return v;
}
__device__ __forceinline__ float block_reduce_max(float v, float* red) {
    const int lane = threadIdx.x & 63, wid = threadIdx.x >> 6;
    v = wave_reduce_max(v);
    if (lane == 0) red[wid] = v;
    __syncthreads();
    v = fmaxf(fmaxf(red[0], red[1]), fmaxf(red[2], red[3]));
    __syncthreads();
    return v;
}

// HW fp8 pack/unpack (gfx950: OCP e4m3fn; self-consistent encode+decode)
__device__ __forceinline__ unsigned int pack4_fp8(float q0, float q1, float q2, float q3) {
    int u = 0;
    u = __builtin_amdgcn_cvt_pk_fp8_f32(q0, q1, u, false);  // bytes 0-1
    u = __builtin_amdgcn_cvt_pk_fp8_f32(q2, q3, u, true);   // bytes 2-3
    return (unsigned int)u;
}

// ---------------- stats: As (fp16) / Cs (fp32) partials + d^2 fp8 stash ----------------
// d8 store per channel: one dword per thread, wave-dense (lane i <-> consecutive uints).
template<int C, int HW, int NT>
__device__ void stats_level(const float* __restrict__ s, const float* __restrict__ t,
                            __half* __restrict__ APs, __half* __restrict__ APt,
                            float* __restrict__ CPs, float* __restrict__ CPt,
                            unsigned int* __restrict__ d8,   // uint view of this level's fp8 region
                            int b, int tile, int chunk, float (*part)[256]) {
    const int tid = threadIdx.x, lane = tid & 63, wid = tid >> 6;
    const int hw0 = tile * HWT + tid * 4;
    const int c0 = chunk * CCH;
    const size_t base = ((size_t)(b * C + c0)) * HW + hw0;
    const float4* ps = reinterpret_cast<const float4*>(s + base);
    const float4* pt = reinterpret_cast<const float4*>(t + base);
    unsigned int* dp = d8 + (((size_t)(b * C + c0)) * (HW / 4) + (hw0 >> 2));
    const int cstride = HW / 4;   // per-channel stride in float4 / uint units

    float as0 = 0.f, as1 = 0.f, as2 = 0.f, as3 = 0.f;
    float at0 = 0.f, at1 = 0.f, at2 = 0.f, at3 = 0.f;
    float css[CCH], cst[CCH];

#pragma unroll
    for (int ci = 0; ci < CCH; ++ci) {
        float4 vs = ps[(size_t)ci * cstride];
        float4 vt = pt[(size_t)ci * cstride];
        float a0 = fabsf(vs.x), a1 = fabsf(vs.y), a2 = fabsf(vs.z), a3 = fabsf(vs.w);
        float b0 = fabsf(vt.x), b1 = fabsf(vt.y), b2 = fabsf(vt.z), b3 = fabsf(vt.w);
        as0 += a0; as1 += a1; as2 += a2; as3 += a3;
        at0 += b0; at1 += b1; at2 += b2; at3 += b3;
        css[ci] = (a0 + a1) + (a2 + a3);
        cst[ci] = (b0 + b1) + (b2 + b3);
        const float d0 = vs.x - vt.x, d1 = vs.y - vt.y, d2 = vs.z - vt.z, d3 = vs.w - vt.w;
        dp[(size_t)ci * cstride] = pack4_fp8(d0 * d0, d1 * d1, d2 * d2, d3 * d3);
    }
    // As partials: fp16 h4 store (8B, aligned: hw0 % 4 == 0)
    const size_t apH = ((size_t)chunk * B_ + b) * HW + hw0;
    h4 hs, ht;
    hs.a = __floats2half2_rn(as0, as1); hs.b = __floats2half2_rn(as2, as3);
    ht.a = __floats2half2_rn(at0, at1); ht.b = __floats2half2_rn(at2, at3);
    *reinterpret_cast<h4*>(APs + apH) = hs;
    *reinterpret_cast<h4*>(APt + apH) = ht;

    // Cs partials: LDS transpose + wave reduce, fp32 plain stores
#pragma unroll
    for (int ci = 0; ci < CCH; ++ci) {
        part[ci][tid] = css[ci];
        part[CCH + ci][tid] = cst[ci];
    }
    __syncthreads();
#pragma unroll
    for (int k = 0; k < 4; ++k) {
        const int r = wid * 4 + k;
        const float* cb = part[r];
        float v = (cb[lane] + cb[lane + 64]) + (cb[lane + 128] + cb[lane + 192]);
        v = wave_reduce_sum(v);
        if (lane == 0) {
            const int cc = r & (CCH - 1);
            float* dst = (r < CCH) ? CPs : CPt;
            dst[((size_t)b * C + c0 + cc) * NT + tile] = v;
        }
    }
}

__global__ __launch_bounds__(256) void stats_fast(const float* __restrict__ s1, const float* __restrict__ t1,
                                                  const float* __restrict__ s2, const float* __restrict__ t2,
                                                  float* ws) {
    __shared__ float part[2 * CCH][256];   // 16 KB
    const int bid = blockIdx.x;
    __half* aph = reinterpret_cast<__half*>(ws + F_APH);
    unsigned int* d8 = reinterpret_cast<unsigned int*>(ws + F_D8);
    if (bid < NB1) {
        const int b = bid >> 7, rem = bid & 127, tile = rem >> 5, chunk = rem & 31;
        stats_level<C1, HW1, NT1>(s1, t1, aph, aph + NH1, ws + F_CP1S, ws + F_CP1T,
                                  d8, b, tile, chunk, part);
    } else {
        const int bid2 = bid - NB1;
        const int b = bid2 >> 6, chunk = bid2 & 63;
        stats_level<C2, HW2, NT2>(s2, t2, aph + 2 * NH1, aph + 2 * NH1 + NH2, ws + F_CP2S, ws + F_CP2T,
                                  d8 + ND1 / 4, b, 0, chunk, part);
    }
}

// ---------------- reduce_as: fold fp16 As partials -> fp32 Gs ----------------
__global__ __launch_bounds__(256) void reduce_as(float* __restrict__ ws) {
    const int gid = blockIdx.x * 256 + threadIdx.x;
    const __half* aph = reinterpret_cast<const __half*>(ws + F_APH);
    if (gid < 2 * B_ * (HW1 / 4)) {                    // level 1
        const int tt = gid >> 13, rem = gid & 8191;
        const int b = rem >> 10, q = rem & 1023;       // HW1/4 = 1024
        const h4* src = reinterpret_cast<const h4*>(aph + (tt ? NH1 : 0))
                        + (size_t)b * (HW1 / 4) + q;
        float4 acc = make_float4(0.f, 0.f, 0.f, 0.f);
#pragma unroll
        for (int k = 0; k < NCH1; ++k) {
            const h4 v = src[(size_t)k * B_ * (HW1 / 4)];
            const float2 lo = __half22float2(v.a), hi = __half22float2(v.b);
            acc.x += lo.x; acc.y += lo.y; acc.z += hi.x; acc.w += hi.y;
        }
        reinterpret_cast<float4*>(ws + (tt ? F_GS1T : F_GS1S))[(size_t)b * (HW1 / 4) + q] = acc;
    } else {                                           // level 2
        const int g2 = gid - 2 * B_ * (HW1 / 4);
        const int tt = g2 >> 11, rem = g2 & 2047;
        const int b = rem >> 8, q = rem & 255;         // HW2/4 = 256
        const h4* src = reinterpret_cast<const h4*>(aph + 2 * NH1 + (tt ? NH2 : 0))
                        + (size_t)b * (HW2 / 4) + q;
        float4 acc = make_float4(0.f, 0.f, 0.f, 0.f);
#pragma unroll
        for (int k = 0; k < NCH2; ++k) {
            const h4 v = src[(size_t)k * B_ * (HW2 / 4)];
            const float2 lo = __half22float2(v.a), hi = __half22float2(v.b);
            acc.x += lo.x; acc.y += lo.y; acc.z += hi.x; acc.w += hi.y;
        }
        reinterpret_cast<float4*>(ws + (tt ? F_GS2T : F_GS2S))[(size_t)b * (HW2 / 4) + q] = acc;
    }
}

// ---------------- softmax + lat (exp cached in LDS; HW __expf) ----------------
__global__ __launch_bounds__(256) void softmax_fast(float* ws) {
    __shared__ float sa[HW1], sb[HW1];
    __shared__ float red[4];
    const int bid = blockIdx.x;
    const int b = bid >> 2, m = bid & 3;
    const int tid = threadIdx.x;

    int n; float scale, mult; float* M;
    if (m == 0)      { n = HW1; scale = 1.0f / C1;  mult = (float)HW1; M = ws + F_MS1 + b * HW1; }
    else if (m == 1) { n = C1;  scale = 1.0f / HW1; mult = (float)C1;  M = ws + F_MC1 + b * C1;  }
    else if (m == 2) { n = HW2; scale = 1.0f / C2;  mult = (float)HW2; M = ws + F_MS2 + b * HW2; }
    else             { n = C2;  scale = 1.0f / HW2; mult = (float)C2;  M = ws + F_MC2 + b * C2;  }

    if (m == 0) {
        const float* As = ws + F_GS1S + b * HW1;
        const float* At = ws + F_GS1T + b * HW1;
        for (int i = tid; i < HW1; i += 256) { sa[i] = As[i] * scale; sb[i] = At[i] * scale; }
    } else if (m == 1) {
        if (tid < C1) {
            float4 v = *reinterpret_cast<const float4*>(ws + F_CP1S + ((size_t)b * C1 + tid) * 4);
            float4 w = *reinterpret_cast<const float4*>(ws + F_CP1T + ((size_t)b * C1 + tid) * 4);
            sa[tid] = ((v.x + v.y) + (v.z + v.w)) * scale;
            sb[tid] = ((w.x + w.y) + (w.z + w.w)) * scale;
        }
    } else if (m == 2) {
        const float* As = ws + F_GS2S + b * HW2;
        const float* At = ws + F_GS2T + b * HW2;
        for (int i = tid; i < HW2; i += 256) { sa[i] = As[i] * scale; sb[i] = At[i] * scale; }
    } else {
        for (int i = tid; i < C2; i += 256) {
            sa[i] = ws[F_CP2S + b * C2 + i] * scale;
            sb[i] = ws[F_CP2T + b * C2 + i] * scale;
        }
    }
    __syncthreads();

    const float invT = 2.0f;  // 1/T, T=0.5
    float latp = 0.f, mx = -3.0e38f;
    for (int i = tid; i < n; i += 256) {
        float d = sa[i] - sb[i];
        latp += d * d;
        mx = fmaxf(mx, (sa[i] + sb[i]) * invT);
    }
    const float mxall = block_reduce_max(mx, red);
    const float latall = block_reduce_sum(latp, red);
    if (tid == 0) ws[F_LATP + bid] = latall;

    // exp pass: compute once, cache in sa (each thread touches only its own slots)
    float se = 0.f;
    for (int i = tid; i < n; i += 256) {
        const float e = __expf((sa[i] + sb[i]) * invT - mxall);
        sa[i] = e;
        se += e;
    }
    const float seall = block_reduce_sum(se, red);
    const float inv = mult / seall;
    for (int i = tid; i < n; i += 256)
        M[i] = sa[i] * inv;
}

// ---------------- slam from fp8 d^2 stash: plain slot write, NO fences ----------------
template<int C, int HW>
__device__ float slam_level(const unsigned int* __restrict__ d8,
                            const float* Ms, const float* Mc,
                            int b, int tile, int chunk, float* mc, float* red) {
    const int tid = threadIdx.x;
    const int hw0 = tile * HWT + tid * 4;
    const int c0 = chunk * CCH;
    if (tid < CCH) mc[tid] = Mc[b * C + c0 + tid];
    __syncthreads();
    const unsigned int* dp = d8 + (((size_t)(b * C + c0)) * (HW / 4) + (hw0 >> 2));
    const int cstride = HW / 4;

    float a0 = 0.f, a1 = 0.f, a2 = 0.f, a3 = 0.f;
#pragma unroll
    for (int ci = 0; ci < CCH; ++ci) {
        const int u = (int)dp[(size_t)ci * cstride];
        const float m = mc[ci];
        const v2f lo = __builtin_amdgcn_cvt_pk_f32_fp8(u, false);
        const v2f hi = __builtin_amdgcn_cvt_pk_f32_fp8(u, true);
        a0 = fmaf(m, lo.x, a0);
        a1 = fmaf(m, lo.y, a1);
        a2 = fmaf(m, hi.x, a2);
        a3 = fmaf(m, hi.y, a3);
    }
    const float4 msv = *reinterpret_cast<const float4*>(Ms + b * HW + hw0);
    float acc = a0 * msv.x + a1 * msv.y + a2 * msv.z + a3 * msv.w;
    return block_reduce_sum(acc, red);
}

__global__ __launch_bounds__(256) void slam_d2(float* __restrict__ ws) {
    __shared__ float mc[CCH];
    __shared__ float red[4];
    const int bid = blockIdx.x;
    const unsigned int* d8 = reinterpret_cast<const unsigned int*>(ws + F_D8);

    if (bid < NB1) {
        const int b = bid >> 7, rem = bid & 127, tile = rem >> 5, chunk = rem & 31;
        float acc = slam_level<C1, HW1>(d8, ws + F_MS1, ws + F_MC1, b, tile, chunk, mc, red);
        if (threadIdx.x == 0) ws[F_SL1P + bid] = acc;
    } else {
        const int bid2 = bid - NB1;
        const int b = bid2 >> 6, chunk = bid2 & 63;
        float acc = slam_level<C2, HW2>(d8 + ND1 / 4, ws + F_MS2, ws + F_MC2, b, 0, chunk, mc, red);
        if (threadIdx.x == 0) ws[F_SL2P + bid2] = acc;
    }
}

// ---------------- final reduction ----------------
__global__ __launch_bounds__(256) void final_fast(const float* __restrict__ ws, float* __restrict__ out) {
    __shared__ float red[4];
    const int tid = threadIdx.x;
    float lat = 0.f, p1 = 0.f, p2 = 0.f;
    for (int i = tid; i < 32; i += 256)   lat += ws[F_LATP + i];
    for (int i = tid; i < NB1; i += 256)  p1 += ws[F_SL1P + i];
    for (int i = tid; i < NB2; i += 256)  p2 += ws[F_SL2P + i];
    lat = block_reduce_sum(lat, red);
    p1 = block_reduce_sum(p1, red);
    p2 = block_reduce_sum(p2, red);
    if (tid == 0) {
        const float lam = sqrtf(p1) + sqrtf(p2);
        const float att = (4e-4f * lat + 2e-2f * lam) / 16.0f;
        out[0] = att * 8.0f;
        out[1] = att;
    }
}

// ============================== launch ==============================

extern "C" void kernel_launch(void* const* d_in, const int* in_sizes, int n_in,
                              void* d_out, int out_size, void* d_ws, size_t ws_size,
                              hipStream_t stream) {
    (void)in_sizes; (void)n_in; (void)out_size; (void)ws_size;
    const float* s1 = (const float*)d_in[1];
    const float* t1 = (const float*)d_in[2];
    const float* s2 = (const float*)d_in[3];
    const float* t2 = (const float*)d_in[4];
    float* ws = (float*)d_ws;
    float* out = (float*)d_out;

    stats_fast<<<NBS, 256, 0, stream>>>(s1, t1, s2, t2, ws);
    reduce_as<<<80, 256, 0, stream>>>(ws);
    softmax_fast<<<32, 256, 0, stream>>>(ws);
    slam_d2<<<NBS, 256, 0, stream>>>(ws);
    final_fast<<<1, 256, 0, stream>>>(ws, out);
}